// Round 12
// baseline (347.302 us; speedup 1.0000x reference)
//
#include <hip/hip_runtime.h>
#include <hip/hip_bf16.h>

typedef __hip_bfloat16 bf16;
typedef short v8s __attribute__((ext_vector_type(8)));   // 8 bf16 (4 VGPRs), MFMA A/B frag
typedef float v4f __attribute__((ext_vector_type(4)));   // MFMA C/D frag

constexpr int NN    = 50000;   // nodes
constexpr int NE    = 800000;  // raw edges (self-loops handled analytically)
constexpr int CIN   = 256;
constexpr int HC    = 256;     // H*C
constexpr int NH    = 4;
constexpr int NOUT  = 40;
constexpr int NPAD  = 48;      // W2T padded cols (3 x 16)
constexpr int SCB   = 196;     // scan blocks (196*256 >= NN)
constexpr int B1    = 128;     // bucket-scatter blocks
constexpr int CH    = (NE + B1 - 1) / B1;   // 6250 edges/chunk
constexpr int NB    = (NN + 255) >> 8;      // 196 dst-buckets (d>>8)

// ---------------- workspace layout ----------------
constexpr size_t al256(size_t x){ return (x + 255) & ~(size_t)255; }
constexpr size_t WS_FLAGS = 0;                                   // 2 ints
constexpr size_t WS_EW1   = 256;                                 // NE float4
constexpr size_t WS_W1T   = al256(WS_EW1   + (size_t)NE*16);     // [n][k] 256x256 bf16
constexpr size_t WS_AS1N  = al256(WS_W1T   + (size_t)CIN*HC*2);
constexpr size_t WS_AD1N  = al256(WS_AS1N  + HC*2);
constexpr size_t WS_B1N   = al256(WS_AD1N  + HC*2);
constexpr size_t WS_W2T   = al256(WS_B1N   + HC*2);              // [n][k] 48x256 bf16 (zero-padded)
constexpr size_t WS_AS2N  = al256(WS_W2T   + (size_t)NPAD*HC*2);
constexpr size_t WS_AD2N  = al256(WS_AS2N  + NOUT*2);
constexpr size_t WS_B2N   = al256(WS_AD2N  + NOUT*2);
constexpr size_t WS_COUNTS= al256(WS_B2N   + NOUT*2);
constexpr size_t WS_CURSOR= al256(WS_COUNTS+ (size_t)NN*4);
constexpr size_t WS_ROWPTR= al256(WS_CURSOR+ (size_t)NN*4);
constexpr size_t WS_EIDX  = al256(WS_ROWPTR+ (size_t)(NN+1)*4);  // NE int (src per CSR slot)
constexpr size_t WS_H1    = al256(WS_EIDX  + (size_t)NE*4);      // NN*HC fp8 (1B)
constexpr size_t WS_ALS1  = al256(WS_H1    + (size_t)NN*HC);
constexpr size_t WS_ALD1  = al256(WS_ALS1  + (size_t)NN*NH*4);
constexpr size_t WS_Y1    = al256(WS_ALD1  + (size_t)NN*NH*4);   // NN*HC bf16
constexpr size_t WS_H2    = al256(WS_Y1    + (size_t)NN*HC*2);   // NN*NOUT bf16
constexpr size_t WS_ALS2  = al256(WS_H2    + (size_t)NN*NOUT*2);
constexpr size_t WS_ALD2  = al256(WS_ALS2  + (size_t)NN*4);
constexpr size_t WS_EW2   = al256(WS_ALD2  + (size_t)NN*4);      // NE float
constexpr size_t WS_BSUM  = al256(WS_EW2   + (size_t)NE*4);      // 256 int
constexpr size_t WS_BOFF  = al256(WS_BSUM  + 1024);              // 256 int
constexpr size_t WS_GCNT  = al256(WS_BOFF  + 1024);              // 256*B1 int
constexpr size_t WS_ROFF  = al256(WS_GCNT  + (size_t)256*B1*4);  // 256*B1 int
constexpr size_t WS_BBASE = al256(WS_ROFF  + (size_t)256*B1*4);  // 257 int
constexpr size_t WS_EBUF  = al256(WS_BBASE + 1056);              // NE int2

// ---------------- convert virtual index space (weights + histogram) ---------
constexpr int CV_W1  = 0;
constexpr int CV_AS1 = CV_W1  + CIN*HC;
constexpr int CV_AD1 = CV_AS1 + HC;
constexpr int CV_B1  = CV_AD1 + HC;
constexpr int CV_W2  = CV_B1  + HC;
constexpr int CV_AS2 = CV_W2  + HC*NOUT;
constexpr int CV_AD2 = CV_AS2 + NOUT;
constexpr int CV_B2  = CV_AD2 + NOUT;
constexpr int CV_HIST= CV_B2  + NOUT;
constexpr int CV_END = CV_HIST + NE;

__device__ __forceinline__ float b2f(bf16 v) { return __bfloat162float(v); }
__device__ __forceinline__ bf16  f2b(float v){ return __float2bfloat16(v); }
__device__ __forceinline__ float bits2f(unsigned short u){ return __uint_as_float(((unsigned)u) << 16); }
__device__ __forceinline__ unsigned short f2bits(float v){
  bf16 t = __float2bfloat16(v);
  return *reinterpret_cast<unsigned short*>(&t);
}
__device__ __forceinline__ float lrelu(float x){ return x > 0.f ? x : 0.2f * x; }

__device__ __forceinline__ float wave_sum(float v){
  #pragma unroll
  for (int off = 32; off; off >>= 1) v += __shfl_xor(v, off, 64);
  return v;
}
__device__ __forceinline__ float wave_max(float v){
  #pragma unroll
  for (int off = 32; off; off >>= 1) v = fmaxf(v, __shfl_xor(v, off, 64));
  return v;
}

// ---------------- dtype detection ----------------
__global__ __launch_bounds__(64) void k_detect(const unsigned short* __restrict__ xu,
                                               const unsigned* __restrict__ eu,
                                               int* __restrict__ flags){
  int lane = threadIdx.x;
  int cnt = 0;
  for (int i = lane; i < 256; i += 64){
    int e = (xu[i] >> 7) & 0xFF;
    cnt += (e >= 0x60 && e <= 0x8F) ? 1 : 0;
  }
  #pragma unroll
  for (int off = 32; off; off >>= 1) cnt += __shfl_xor(cnt, off, 64);
  unsigned odd = eu[2 * lane + 1];
  #pragma unroll
  for (int off = 32; off; off >>= 1) odd |= __shfl_xor(odd, off, 64);
  if (lane == 0){
    flags[0] = (cnt < 218) ? 1 : 0;   // 1 = floats are f32
    flags[1] = (odd == 0)  ? 1 : 0;   // 1 = edges are int64
  }
}

__device__ __forceinline__ bf16 cvt_b(const void* src, int i, int f32m){
  if (f32m) return __float2bfloat16(((const float*)src)[i]);
  return ((const bf16*)src)[i];
}

// convert (weights only) + histogram over dst read straight from d_in
__global__ __launch_bounds__(256) void k_convert(
    const void* __restrict__ W1,
    const void* __restrict__ as1,const void* __restrict__ ad1,
    const void* __restrict__ b1, const void* __restrict__ W2,
    const void* __restrict__ as2,const void* __restrict__ ad2,
    const void* __restrict__ b2, const void* __restrict__ ei,
    char* __restrict__ ws){
  const int* flags = (const int*)(ws + WS_FLAGS);
  int f32m = flags[0], i64m = flags[1];
  bf16* w1t  = (bf16*)(ws + WS_W1T);
  bf16* as1n = (bf16*)(ws + WS_AS1N);
  bf16* ad1n = (bf16*)(ws + WS_AD1N);
  bf16* b1n  = (bf16*)(ws + WS_B1N);
  bf16* w2t  = (bf16*)(ws + WS_W2T);
  bf16* as2n = (bf16*)(ws + WS_AS2N);
  bf16* ad2n = (bf16*)(ws + WS_AD2N);
  bf16* b2n  = (bf16*)(ws + WS_B2N);
  int*  counts=(int*) (ws + WS_COUNTS);
  for (int g = blockIdx.x * 256 + threadIdx.x; g < CV_END; g += gridDim.x * 256){
    if      (g < CV_AS1){ int i = g-CV_W1; int k = i >> 8, n = i & 255;
      w1t[n*CIN + k] = cvt_b(W1, i, f32m); }                       // transpose
    else if (g < CV_AD1) as1n[g-CV_AS1] = cvt_b(as1,g-CV_AS1, f32m);
    else if (g < CV_B1 ) ad1n[g-CV_AD1] = cvt_b(ad1,g-CV_AD1, f32m);
    else if (g < CV_W2 ) b1n [g-CV_B1 ] = cvt_b(b1, g-CV_B1,  f32m);
    else if (g < CV_AS2){ int i = g-CV_W2; int k = i / NOUT, n = i - k*NOUT;
      w2t[n*CIN + k] = cvt_b(W2, i, f32m); }                       // transpose (rows 40..47 pre-zeroed)
    else if (g < CV_AD2) as2n[g-CV_AS2] = cvt_b(as2,g-CV_AS2, f32m);
    else if (g < CV_B2 ) ad2n[g-CV_AD2] = cvt_b(ad2,g-CV_AD2, f32m);
    else if (g < CV_HIST) b2n[g-CV_B2 ] = cvt_b(b2, g-CV_B2,  f32m);
    else { int i = g-CV_HIST;
      int d = i64m ? (int)((const long long*)ei)[(size_t)NE+i] : ((const int*)ei)[NE+i];
      atomicAdd(&counts[d], 1); }
  }
}

// ---------------- parallel CSR scan (real edges only; self-loops analytic) -----
__global__ __launch_bounds__(256) void k_scan_part(const int* __restrict__ counts, int* __restrict__ bsum){
  __shared__ int lds[256];
  int t = threadIdx.x;
  int idx = blockIdx.x * 256 + t;
  int v = (idx < NN) ? counts[idx] : 0;
  lds[t] = v;
  #pragma unroll
  for (int s = 128; s > 0; s >>= 1){
    __syncthreads();
    if (t < s) lds[t] += lds[t + s];
  }
  if (t == 0) bsum[blockIdx.x] = lds[0];
}

__global__ __launch_bounds__(256) void k_scan_mid(const int* __restrict__ bsum, int* __restrict__ boff,
                                                  int* __restrict__ row_ptr){
  __shared__ int lds[256];
  int t = threadIdx.x;
  int v = (t < SCB) ? bsum[t] : 0;
  lds[t] = v;
  for (int off = 1; off < 256; off <<= 1){
    __syncthreads();
    int u = (t >= off) ? lds[t - off] : 0;
    __syncthreads();
    lds[t] += u;
  }
  __syncthreads();
  if (t < SCB) boff[t] = lds[t] - v;   // exclusive
  if (t == 0) row_ptr[NN] = NE;
}

__global__ __launch_bounds__(256) void k_scan_apply(const int* __restrict__ counts, const int* __restrict__ boff,
                                                    int* __restrict__ row_ptr){
  __shared__ int lds[256];
  int t = threadIdx.x;
  int idx = blockIdx.x * 256 + t;
  int v = (idx < NN) ? counts[idx] : 0;
  lds[t] = v;
  for (int off = 1; off < 256; off <<= 1){
    __syncthreads();
    int u = (t >= off) ? lds[t - off] : 0;
    __syncthreads();
    lds[t] += u;
  }
  __syncthreads();
  if (idx < NN) row_ptr[idx] = boff[blockIdx.x] + lds[t] - v;
}

// ---------------- bucket partition (replaces random scatter) ----------------
// Pass 1: per-(block,bucket) histogram. bucket = d >> 8 (196 buckets).
__global__ __launch_bounds__(256) void k_lhist(const void* __restrict__ ei, const int* __restrict__ flags,
                                               int* __restrict__ gcnt){
  __shared__ int h[256];
  int tid = threadIdx.x, blk = blockIdx.x;
  h[tid] = 0;
  __syncthreads();
  int i0 = blk * CH, i1 = min(i0 + CH, NE);
  int i64m = flags[1];
  for (int i = i0 + tid; i < i1; i += 256){
    int d = i64m ? (int)((const long long*)ei)[(size_t)NE + i] : ((const int*)ei)[NE + i];
    atomicAdd(&h[d >> 8], 1);
  }
  __syncthreads();
  gcnt[tid * B1 + blk] = h[tid];    // layout [bucket][block]
}

// Pass 2: scan (bucket,block) counts -> run offsets + bucket bases (1 block)
__global__ __launch_bounds__(256) void k_gscan(const int* __restrict__ gcnt, int* __restrict__ roff,
                                               int* __restrict__ bbase){
  __shared__ int lds[256];
  int t = threadIdx.x;
  int tot = 0;
  for (int blk = 0; blk < B1; ++blk) tot += gcnt[t * B1 + blk];
  lds[t] = tot;
  for (int off = 1; off < 256; off <<= 1){
    __syncthreads();
    int u = (t >= off) ? lds[t - off] : 0;
    __syncthreads();
    lds[t] += u;
  }
  __syncthreads();
  int base = lds[t] - tot;          // exclusive over buckets
  bbase[t] = base;
  if (t == 255) bbase[256] = NE;
  int run = base;
  for (int blk = 0; blk < B1; ++blk){
    roff[t * B1 + blk] = run;
    run += gcnt[t * B1 + blk];
  }
}

// Pass 3: append edges into block-exclusive contiguous runs (block-local lines)
__global__ __launch_bounds__(256) void k_bscatter(const void* __restrict__ ei, const int* __restrict__ flags,
                                                  const int* __restrict__ roff, int2* __restrict__ ebuf){
  __shared__ int lcur[256];
  int tid = threadIdx.x, blk = blockIdx.x;
  lcur[tid] = roff[tid * B1 + blk];
  __syncthreads();
  int i0 = blk * CH, i1 = min(i0 + CH, NE);
  int i64m = flags[1];
  for (int i = i0 + tid; i < i1; i += 256){
    int s, d;
    if (i64m){ s = (int)((const long long*)ei)[i]; d = (int)((const long long*)ei)[(size_t)NE + i]; }
    else     { s = ((const int*)ei)[i];            d = ((const int*)ei)[NE + i]; }
    int pos = atomicAdd(&lcur[d >> 8], 1);
    ebuf[pos] = make_int2(s, d);
  }
}

// Pass 4: refine within bucket to exact CSR position (block owns bucket's row range)
__global__ __launch_bounds__(256) void k_refine(const int2* __restrict__ ebuf, const int* __restrict__ bbase,
                                                const int* __restrict__ row_ptr, int* __restrict__ cursor,
                                                int* __restrict__ eidx){
  int b = blockIdx.x;
  int p0 = bbase[b], p1 = bbase[b + 1];
  for (int p = p0 + threadIdx.x; p < p1; p += 256){
    int2 e = ebuf[p];
    int pos = row_ptr[e.y] + atomicAdd(&cursor[e.y], 1);
    eidx[pos] = e.x;
  }
}

// ---------------- GEMM1 (MFMA, LDS-staged) + fused al1 + fp8 h1 store ---------
constexpr int G1R = 64;                 // rows per block
constexpr int LP  = 72;                 // padded LDS row (elems)
__global__ __launch_bounds__(256) void k_gemm1(const void* __restrict__ xin,
                                               const int* __restrict__ flags,
                                               const bf16* __restrict__ w1t,
                                               const bf16* __restrict__ as1, const bf16* __restrict__ ad1,
                                               unsigned char* __restrict__ h1q,
                                               float* __restrict__ al_s1, float* __restrict__ al_d1){
  __shared__ short Ab[G1R * LP];
  __shared__ short Bb[256 * LP];
  int tid  = threadIdx.x;
  int w    = tid >> 6, lane = tid & 63, quad = lane >> 4, c = lane & 15;
  int row0 = blockIdx.x * G1R;
  int f32m = flags[0];

  v4f acc[4][4];
  #pragma unroll
  for (int mt = 0; mt < 4; ++mt)
    #pragma unroll
    for (int nt = 0; nt < 4; ++nt) acc[mt][nt] = (v4f){0.f,0.f,0.f,0.f};

  int arow = tid >> 2;
  int aseg = tid & 3;
  int grow = row0 + arow; if (grow >= NN) grow = NN - 1;

  for (int ph = 0; ph < 4; ++ph){
    if (ph) __syncthreads();
    {
      short va[16];
      if (f32m){
        const float* src = (const float*)xin + (size_t)grow * CIN + ph*64 + aseg*16;
        #pragma unroll
        for (int i = 0; i < 4; ++i){
          float4 f = *reinterpret_cast<const float4*>(src + i*4);
          va[i*4+0] = (short)f2bits(f.x); va[i*4+1] = (short)f2bits(f.y);
          va[i*4+2] = (short)f2bits(f.z); va[i*4+3] = (short)f2bits(f.w);
        }
      } else {
        const short* src = (const short*)xin + (size_t)grow * CIN + ph*64 + aseg*16;
        v8s u0 = *reinterpret_cast<const v8s*>(src);
        v8s u1 = *reinterpret_cast<const v8s*>(src + 8);
        #pragma unroll
        for (int i = 0; i < 8; ++i){ va[i] = u0[i]; va[8+i] = u1[i]; }
      }
      short* dst = &Ab[arow * LP + aseg * 16];
      *reinterpret_cast<v8s*>(dst)     = *reinterpret_cast<v8s*>(&va[0]);
      *reinterpret_cast<v8s*>(dst + 8) = *reinterpret_cast<v8s*>(&va[8]);
    }
    {
      const short* src = (const short*)w1t + (size_t)tid * CIN + ph*64;
      short* dst = &Bb[tid * LP];
      #pragma unroll
      for (int j = 0; j < 8; ++j)
        *reinterpret_cast<v8s*>(dst + j*8) = *reinterpret_cast<const v8s*>(src + j*8);
    }
    __syncthreads();
    #pragma unroll
    for (int s = 0; s < 2; ++s){
      int ch = s*4 + quad;
      v8s af[4], bfb[4];
      #pragma unroll
      for (int mt = 0; mt < 4; ++mt)
        af[mt] = *reinterpret_cast<const v8s*>(&Ab[(mt*16 + c) * LP + ch*8]);
      #pragma unroll
      for (int nt = 0; nt < 4; ++nt)
        bfb[nt] = *reinterpret_cast<const v8s*>(&Bb[(w*64 + nt*16 + c) * LP + ch*8]);
      #pragma unroll
      for (int mt = 0; mt < 4; ++mt)
        #pragma unroll
        for (int nt = 0; nt < 4; ++nt)
          acc[mt][nt] = __builtin_amdgcn_mfma_f32_16x16x32_bf16(af[mt], bfb[nt], acc[mt][nt], 0, 0, 0);
    }
  }

  float as1v[4], ad1v[4];
  #pragma unroll
  for (int nt = 0; nt < 4; ++nt){
    as1v[nt] = b2f(as1[w*64 + nt*16 + c]);
    ad1v[nt] = b2f(ad1[w*64 + nt*16 + c]);
  }
  #pragma unroll
  for (int mt = 0; mt < 4; ++mt){
    #pragma unroll
    for (int r = 0; r < 4; ++r){
      float ps = 0.f, pd = 0.f;
      #pragma unroll
      for (int nt = 0; nt < 4; ++nt){ ps += acc[mt][nt][r] * as1v[nt]; pd += acc[mt][nt][r] * ad1v[nt]; }
      #pragma unroll
      for (int off = 1; off < 16; off <<= 1){ ps += __shfl_xor(ps, off, 64); pd += __shfl_xor(pd, off, 64); }
      int row = row0 + mt*16 + quad*4 + r;
      if (c == 0 && row < NN){
        al_s1[row * NH + w] = ps;
        al_d1[row * NH + w] = pd;
      }
    }
  }
  #pragma unroll
  for (int mt = 0; mt < 4; ++mt){
    #pragma unroll
    for (int nt = 0; nt < 4; ++nt){
      #pragma unroll
      for (int r = 0; r < 4; r += 2){
        int row = row0 + mt*16 + quad*4 + r;
        if (row + 1 < NN){
          int pk = __builtin_amdgcn_cvt_pk_fp8_f32(acc[mt][nt][r], acc[mt][nt][r+1], 0, false);
          size_t col = w*64 + nt*16 + c;
          h1q[(size_t)row       * HC + col] = (unsigned char)(pk & 0xFF);
          h1q[(size_t)(row + 1) * HC + col] = (unsigned char)((pk >> 8) & 0xFF);
        } else if (row < NN){
          int pk = __builtin_amdgcn_cvt_pk_fp8_f32(acc[mt][nt][r], acc[mt][nt][r], 0, false);
          h1q[(size_t)row * HC + w*64 + nt*16 + c] = (unsigned char)(pk & 0xFF);
        }
      }
    }
  }
}

// ---------------- edge weights layer 1 (node-parallel: coalesced ew writes) ----
__global__ __launch_bounds__(256) void k_ew1(const int* __restrict__ row_ptr, const int* __restrict__ eidx,
                                             const float* __restrict__ al_s1, const float* __restrict__ al_d1,
                                             float4* __restrict__ ew1){
  int lane = threadIdx.x & 63;
  int n = blockIdx.x * 4 + (threadIdx.x >> 6);
  int p0 = __builtin_amdgcn_readfirstlane(row_ptr[n]);
  int p1 = __builtin_amdgcn_readfirstlane(row_ptr[n + 1]);
  float4 ad = reinterpret_cast<const float4*>(al_d1)[n];   // wave-uniform
  for (int p = p0 + lane; p < p1; p += 64){
    int s = eidx[p];
    float4 as = reinterpret_cast<const float4*>(al_s1)[s];
    float4 w;
    w.x = __expf(lrelu(as.x + ad.x));
    w.y = __expf(lrelu(as.y + ad.y));
    w.z = __expf(lrelu(as.z + ad.z));
    w.w = __expf(lrelu(as.w + ad.w));
    ew1[p] = w;
  }
}

// ---------------- gather layer 1 (+ analytic self-loop) ----------------
__global__ __launch_bounds__(256) void k_gather1(const int* __restrict__ row_ptr, const int* __restrict__ eidx,
                                                 const float* __restrict__ ew1,
                                                 const float* __restrict__ al_s1, const float* __restrict__ al_d1,
                                                 const unsigned* __restrict__ h1v, const bf16* __restrict__ b1,
                                                 bf16* __restrict__ y1){
  int lane = threadIdx.x & 63;
  int n = blockIdx.x * 4 + (threadIdx.x >> 6);
  int h = lane >> 4;
  int p0 = __builtin_amdgcn_readfirstlane(row_ptr[n]);
  int p1 = __builtin_amdgcn_readfirstlane(row_ptr[n + 1]);
  // self-loop contribution (src == dst == n)
  float wss = __expf(lrelu(al_s1[n * NH + h] + al_d1[n * NH + h]));
  unsigned us = h1v[(size_t)n * 64 + lane];
  float den = wss;
  float a0 = wss * __builtin_amdgcn_cvt_f32_fp8(us, 0);
  float a1 = wss * __builtin_amdgcn_cvt_f32_fp8(us, 1);
  float a2 = wss * __builtin_amdgcn_cvt_f32_fp8(us, 2);
  float a3 = wss * __builtin_amdgcn_cvt_f32_fp8(us, 3);
  int p = p0;
  for (; p + 1 < p1; p += 2){
    int sA = __builtin_amdgcn_readfirstlane(eidx[p]);
    int sB = __builtin_amdgcn_readfirstlane(eidx[p + 1]);
    float wA = ew1[(size_t)p * 4 + h];
    float wB = ew1[(size_t)(p + 1) * 4 + h];
    unsigned uA = h1v[(size_t)sA * 64 + lane];
    unsigned uB = h1v[(size_t)sB * 64 + lane];
    den += wA + wB;
    a0 += wA * __builtin_amdgcn_cvt_f32_fp8(uA, 0) + wB * __builtin_amdgcn_cvt_f32_fp8(uB, 0);
    a1 += wA * __builtin_amdgcn_cvt_f32_fp8(uA, 1) + wB * __builtin_amdgcn_cvt_f32_fp8(uB, 1);
    a2 += wA * __builtin_amdgcn_cvt_f32_fp8(uA, 2) + wB * __builtin_amdgcn_cvt_f32_fp8(uB, 2);
    a3 += wA * __builtin_amdgcn_cvt_f32_fp8(uA, 3) + wB * __builtin_amdgcn_cvt_f32_fp8(uB, 3);
  }
  if (p < p1){
    int s = __builtin_amdgcn_readfirstlane(eidx[p]);
    float w = ew1[(size_t)p * 4 + h];
    unsigned u = h1v[(size_t)s * 64 + lane];
    den += w;
    a0 += w * __builtin_amdgcn_cvt_f32_fp8(u, 0);
    a1 += w * __builtin_amdgcn_cvt_f32_fp8(u, 1);
    a2 += w * __builtin_amdgcn_cvt_f32_fp8(u, 2);
    a3 += w * __builtin_amdgcn_cvt_f32_fp8(u, 3);
  }
  float inv = 1.f / (den + 1e-16f);
  ushort4 bb = reinterpret_cast<const ushort4*>(b1)[lane];
  ushort4 o;
  o.x = f2bits(fmaxf(a0 * inv + bits2f(bb.x), 0.f));
  o.y = f2bits(fmaxf(a1 * inv + bits2f(bb.y), 0.f));
  o.z = f2bits(fmaxf(a2 * inv + bits2f(bb.z), 0.f));
  o.w = f2bits(fmaxf(a3 * inv + bits2f(bb.w), 0.f));
  reinterpret_cast<ushort4*>(y1)[(size_t)n * 64 + lane] = o;
}

// ---------------- GEMM2 (MFMA, W2T in LDS) + fused al_s2/al_d2 ----------------
constexpr int W2LP = 260;
__global__ __launch_bounds__(256) void k_gemm2(const bf16* __restrict__ y1, const bf16* __restrict__ w2t,
                                               const bf16* __restrict__ as2, const bf16* __restrict__ ad2,
                                               bf16* __restrict__ h2, float* __restrict__ al_s2,
                                               float* __restrict__ al_d2){
  __shared__ short Wb[NPAD * W2LP];
  int tid = threadIdx.x;
  int w = tid >> 6, lane = tid & 63, quad = lane >> 4, c = lane & 15;
  int m0 = blockIdx.x * 64 + w * 16;
  for (int idx = tid; idx < NPAD * 32; idx += 256){
    int n = idx >> 5, sg = idx & 31;
    *reinterpret_cast<v8s*>(&Wb[n * W2LP + sg * 8]) =
      *reinterpret_cast<const v8s*>((const short*)w2t + (size_t)n * CIN + sg * 8);
  }
  int arow = m0 + c; if (arow >= NN) arow = NN - 1;
  const short* ar = (const short*)y1 + (size_t)arow * HC + quad * 8;
  v8s a[8];
  #pragma unroll
  for (int i = 0; i < 8; ++i) a[i] = *reinterpret_cast<const v8s*>(ar + i * 32);
  __syncthreads();

  v4f acc[3];
  #pragma unroll
  for (int t = 0; t < 3; ++t) acc[t] = (v4f){0.f, 0.f, 0.f, 0.f};
  #pragma unroll
  for (int k = 0; k < 8; ++k){
    int ch = k*4 + quad;
    #pragma unroll
    for (int t = 0; t < 3; ++t){
      v8s b = *reinterpret_cast<const v8s*>(&Wb[(t*16 + c) * W2LP + ch * 8]);
      acc[t] = __builtin_amdgcn_mfma_f32_16x16x32_bf16(a[k], b, acc[t], 0, 0, 0);
    }
  }
  float as2f[3], ad2f[3];
  #pragma unroll
  for (int t = 0; t < 3; ++t){
    int col = t*16 + c;
    as2f[t] = (col < NOUT) ? b2f(as2[col]) : 0.f;
    ad2f[t] = (col < NOUT) ? b2f(ad2[col]) : 0.f;
  }
  #pragma unroll
  for (int r = 0; r < 4; ++r){
    int row = m0 + quad*4 + r;
    float ps = 0.f, pd = 0.f;
    #pragma unroll
    for (int t = 0; t < 3; ++t){ ps += acc[t][r] * as2f[t]; pd += acc[t][r] * ad2f[t]; }
    #pragma unroll
    for (int off = 1; off < 16; off <<= 1){ ps += __shfl_xor(ps, off, 64); pd += __shfl_xor(pd, off, 64); }
    if (row < NN){
      if (c == 0){ al_s2[row] = ps; al_d2[row] = pd; }
      #pragma unroll
      for (int t = 0; t < 3; ++t){
        int col = t*16 + c;
        if (col < NOUT) h2[(size_t)row * NOUT + col] = f2b(acc[t][r]);
      }
    }
  }
}

// ---------------- edge weights layer 2 (node-parallel) ----------------
__global__ __launch_bounds__(256) void k_ew2(const int* __restrict__ row_ptr, const int* __restrict__ eidx,
                                             const float* __restrict__ al_s2, const float* __restrict__ al_d2,
                                             float* __restrict__ ew2){
  int lane = threadIdx.x & 63;
  int n = blockIdx.x * 4 + (threadIdx.x >> 6);
  int p0 = __builtin_amdgcn_readfirstlane(row_ptr[n]);
  int p1 = __builtin_amdgcn_readfirstlane(row_ptr[n + 1]);
  float ad = al_d2[n];   // wave-uniform
  for (int p = p0 + lane; p < p1; p += 64)
    ew2[p] = __expf(lrelu(al_s2[eidx[p]] + ad));
}

// ---------------- gather layer 2 (+ analytic self-loop) + log_softmax ----------
__global__ __launch_bounds__(256) void k_gather2(const int* __restrict__ row_ptr, const int* __restrict__ eidx,
                                                 const float* __restrict__ ew2,
                                                 const float* __restrict__ al_s2, const float* __restrict__ al_d2,
                                                 const bf16* __restrict__ h2, const bf16* __restrict__ b2v,
                                                 const int* __restrict__ flags, void* __restrict__ out){
  int lane = threadIdx.x & 63;
  int n = blockIdx.x * 4 + (threadIdx.x >> 6);
  int p0 = __builtin_amdgcn_readfirstlane(row_ptr[n]);
  int p1 = __builtin_amdgcn_readfirstlane(row_ptr[n + 1]);
  float wss = __expf(lrelu(al_s2[n] + al_d2[n]));
  float den = wss;
  float acc = (lane < NOUT) ? wss * b2f(h2[(size_t)n * NOUT + lane]) : 0.f;
  int p = p0;
  for (; p + 1 < p1; p += 2){
    int sA = __builtin_amdgcn_readfirstlane(eidx[p]);
    int sB = __builtin_amdgcn_readfirstlane(eidx[p + 1]);
    float wA = ew2[p], wB = ew2[p + 1];
    float hA = 0.f, hB = 0.f;
    if (lane < NOUT){
      hA = b2f(h2[(size_t)sA * NOUT + lane]);
      hB = b2f(h2[(size_t)sB * NOUT + lane]);
    }
    den += wA + wB;
    acc += wA * hA + wB * hB;
  }
  if (p < p1){
    int s = __builtin_amdgcn_readfirstlane(eidx[p]);
    float w = ew2[p];
    den += w;
    if (lane < NOUT) acc += w * b2f(h2[(size_t)s * NOUT + lane]);
  }
  float v = (lane < NOUT) ? (acc / (den + 1e-16f) + b2f(b2v[lane])) : -INFINITY;
  float M = wave_max(v);
  float ex = (lane < NOUT) ? __expf(v - M) : 0.f;
  float S = wave_sum(ex);
  if (lane < NOUT){
    float r = v - M - __logf(S);
    size_t idx = (size_t)n * NOUT + lane;
    if (flags[0]) ((float*)out)[idx] = r;
    else          ((bf16*)out)[idx]  = f2b(r);
  }
}

extern "C" void kernel_launch(void* const* d_in, const int* in_sizes, int n_in,
                              void* d_out, int out_size, void* d_ws, size_t ws_size,
                              hipStream_t stream) {
  const void* x   = d_in[0];
  const void* ei  = d_in[1];
  const void* W1  = d_in[2];
  const void* as1 = d_in[3];
  const void* ad1 = d_in[4];
  const void* b1  = d_in[5];
  const void* W2  = d_in[6];
  const void* as2 = d_in[7];
  const void* ad2 = d_in[8];
  const void* b2  = d_in[9];

  char* ws = (char*)d_ws;
  int*   flags   = (int*)  (ws + WS_FLAGS);
  float* ew1     = (float*)(ws + WS_EW1);
  bf16*  w1t     = (bf16*) (ws + WS_W1T);
  bf16*  as1n    = (bf16*) (ws + WS_AS1N);
  bf16*  ad1n    = (bf16*) (ws + WS_AD1N);
  bf16*  b1n     = (bf16*) (ws + WS_B1N);
  bf16*  w2t     = (bf16*) (ws + WS_W2T);
  bf16*  as2n    = (bf16*) (ws + WS_AS2N);
  bf16*  ad2n    = (bf16*) (ws + WS_AD2N);
  bf16*  b2n     = (bf16*) (ws + WS_B2N);
  int*   counts  = (int*)  (ws + WS_COUNTS);
  int*   cursor  = (int*)  (ws + WS_CURSOR);
  int*   row_ptr = (int*)  (ws + WS_ROWPTR);
  int*   eidx    = (int*)  (ws + WS_EIDX);
  unsigned char* h1q = (unsigned char*)(ws + WS_H1);
  float* al_s1   = (float*)(ws + WS_ALS1);
  float* al_d1   = (float*)(ws + WS_ALD1);
  bf16*  y1      = (bf16*) (ws + WS_Y1);
  bf16*  h2      = (bf16*) (ws + WS_H2);
  float* al_s2   = (float*)(ws + WS_ALS2);
  float* al_d2   = (float*)(ws + WS_ALD2);
  float* ew2     = (float*)(ws + WS_EW2);
  int*   bsum    = (int*)  (ws + WS_BSUM);
  int*   boff    = (int*)  (ws + WS_BOFF);
  int*   gcnt    = (int*)  (ws + WS_GCNT);
  int*   roff    = (int*)  (ws + WS_ROFF);
  int*   bbase   = (int*)  (ws + WS_BBASE);
  int2*  ebuf    = (int2*) (ws + WS_EBUF);

  hipMemsetAsync(counts, 0, (size_t)NN * 4, stream);
  hipMemsetAsync(cursor, 0, (size_t)NN * 4, stream);
  hipMemsetAsync(w2t,    0, (size_t)NPAD * CIN * 2, stream);

  k_detect <<<1, 64, 0, stream>>>((const unsigned short*)x, (const unsigned*)ei, flags);
  k_convert<<<1024, 256, 0, stream>>>(W1, as1, ad1, b1, W2, as2, ad2, b2, ei, ws);

  k_lhist   <<<B1, 256, 0, stream>>>(ei, flags, gcnt);
  k_gscan   <<<1, 256, 0, stream>>>(gcnt, roff, bbase);
  k_scan_part <<<SCB, 256, 0, stream>>>(counts, bsum);
  k_scan_mid  <<<1, 256, 0, stream>>>(bsum, boff, row_ptr);
  k_scan_apply<<<SCB, 256, 0, stream>>>(counts, boff, row_ptr);
  k_bscatter<<<B1, 256, 0, stream>>>(ei, flags, roff, ebuf);
  k_refine  <<<NB, 256, 0, stream>>>(ebuf, bbase, row_ptr, cursor, eidx);

  k_gemm1  <<<(NN + G1R - 1) / G1R, 256, 0, stream>>>(x, flags, w1t, as1n, ad1n, h1q, al_s1, al_d1);
  k_ew1    <<<NN / 4, 256, 0, stream>>>(row_ptr, eidx, al_s1, al_d1, (float4*)ew1);
  k_gather1<<<NN / 4, 256, 0, stream>>>(row_ptr, eidx, ew1, al_s1, al_d1, (const unsigned*)h1q, b1n, y1);
  k_gemm2  <<<(NN + 63) / 64, 256, 0, stream>>>(y1, w2t, as2n, ad2n, h2, al_s2, al_d2);
  k_ew2    <<<NN / 4, 256, 0, stream>>>(row_ptr, eidx, al_s2, al_d2, ew2);
  k_gather2<<<NN / 4, 256, 0, stream>>>(row_ptr, eidx, ew2, al_s2, al_d2, h2, b2n, flags, d_out);
}

// Round 13
// 329.224 us; speedup vs baseline: 1.0549x; 1.0549x over previous
//
#include <hip/hip_runtime.h>
#include <hip/hip_bf16.h>

typedef __hip_bfloat16 bf16;
typedef short v8s __attribute__((ext_vector_type(8)));   // 8 bf16 (4 VGPRs), MFMA A/B frag
typedef float v4f __attribute__((ext_vector_type(4)));   // MFMA C/D frag

constexpr int NN    = 50000;   // nodes
constexpr int NE    = 800000;  // raw edges (self-loops handled analytically)
constexpr int CIN   = 256;
constexpr int HC    = 256;     // H*C
constexpr int NH    = 4;
constexpr int NOUT  = 40;
constexpr int NPAD  = 48;      // W2T padded cols (3 x 16)
constexpr int SCB   = 196;     // scan blocks (196*256 >= NN)
constexpr int B1    = 128;     // bucket-scatter blocks
constexpr int CH    = (NE + B1 - 1) / B1;   // 6250 edges/chunk
constexpr int NB    = (NN + 255) >> 8;      // 196 dst-buckets (d>>8)

// ---------------- workspace layout ----------------
constexpr size_t al256(size_t x){ return (x + 255) & ~(size_t)255; }
constexpr size_t WS_FLAGS = 0;                                   // 2 ints
constexpr size_t WS_EW1   = 256;                                 // NE float4
constexpr size_t WS_W1T   = al256(WS_EW1   + (size_t)NE*16);     // [n][k] 256x256 bf16
constexpr size_t WS_AS1N  = al256(WS_W1T   + (size_t)CIN*HC*2);
constexpr size_t WS_AD1N  = al256(WS_AS1N  + HC*2);
constexpr size_t WS_B1N   = al256(WS_AD1N  + HC*2);
constexpr size_t WS_W2T   = al256(WS_B1N   + HC*2);              // [n][k] 48x256 bf16 (zero-padded)
constexpr size_t WS_AS2N  = al256(WS_W2T   + (size_t)NPAD*HC*2);
constexpr size_t WS_AD2N  = al256(WS_AS2N  + NOUT*2);
constexpr size_t WS_B2N   = al256(WS_AD2N  + NOUT*2);
constexpr size_t WS_COUNTS= al256(WS_B2N   + NOUT*2);
constexpr size_t WS_CURSOR= al256(WS_COUNTS+ (size_t)NN*4);
constexpr size_t WS_ROWPTR= al256(WS_CURSOR+ (size_t)NN*4);
constexpr size_t WS_EIDX  = al256(WS_ROWPTR+ (size_t)(NN+1)*4);  // NE int (src per CSR slot)
constexpr size_t WS_H1    = al256(WS_EIDX  + (size_t)NE*4);      // NN*HC fp8 (1B)
constexpr size_t WS_ALS1  = al256(WS_H1    + (size_t)NN*HC);
constexpr size_t WS_ALD1  = al256(WS_ALS1  + (size_t)NN*NH*4);
constexpr size_t WS_Y1    = al256(WS_ALD1  + (size_t)NN*NH*4);   // NN*HC bf16
constexpr size_t WS_H2    = al256(WS_Y1    + (size_t)NN*HC*2);   // NN*64 fp8 (64B row = 1 line)
constexpr size_t WS_ALS2  = al256(WS_H2    + (size_t)NN*64);
constexpr size_t WS_ALD2  = al256(WS_ALS2  + (size_t)NN*4);
constexpr size_t WS_EW2   = al256(WS_ALD2  + (size_t)NN*4);      // NE float
constexpr size_t WS_BSUM  = al256(WS_EW2   + (size_t)NE*4);      // 256 int
constexpr size_t WS_BOFF  = al256(WS_BSUM  + 1024);              // 256 int
constexpr size_t WS_GCNT  = al256(WS_BOFF  + 1024);              // 256*B1 int
constexpr size_t WS_ROFF  = al256(WS_GCNT  + (size_t)256*B1*4);  // 256*B1 int
constexpr size_t WS_BBASE = al256(WS_ROFF  + (size_t)256*B1*4);  // 257 int
constexpr size_t WS_EBUF  = al256(WS_BBASE + 1056);              // NE int2

// ---------------- convert virtual index space (weights + histogram) ---------
constexpr int CV_W1  = 0;
constexpr int CV_AS1 = CV_W1  + CIN*HC;
constexpr int CV_AD1 = CV_AS1 + HC;
constexpr int CV_B1  = CV_AD1 + HC;
constexpr int CV_W2  = CV_B1  + HC;
constexpr int CV_AS2 = CV_W2  + HC*NOUT;
constexpr int CV_AD2 = CV_AS2 + NOUT;
constexpr int CV_B2  = CV_AD2 + NOUT;
constexpr int CV_HIST= CV_B2  + NOUT;
constexpr int CV_END = CV_HIST + NE;

__device__ __forceinline__ float b2f(bf16 v) { return __bfloat162float(v); }
__device__ __forceinline__ bf16  f2b(float v){ return __float2bfloat16(v); }
__device__ __forceinline__ float bits2f(unsigned short u){ return __uint_as_float(((unsigned)u) << 16); }
__device__ __forceinline__ unsigned short f2bits(float v){
  bf16 t = __float2bfloat16(v);
  return *reinterpret_cast<unsigned short*>(&t);
}
__device__ __forceinline__ float lrelu(float x){ return x > 0.f ? x : 0.2f * x; }

__device__ __forceinline__ float wave_sum(float v){
  #pragma unroll
  for (int off = 32; off; off >>= 1) v += __shfl_xor(v, off, 64);
  return v;
}
__device__ __forceinline__ float wave_max(float v){
  #pragma unroll
  for (int off = 32; off; off >>= 1) v = fmaxf(v, __shfl_xor(v, off, 64));
  return v;
}

// ---------------- dtype detection ----------------
__global__ __launch_bounds__(64) void k_detect(const unsigned short* __restrict__ xu,
                                               const unsigned* __restrict__ eu,
                                               int* __restrict__ flags){
  int lane = threadIdx.x;
  int cnt = 0;
  for (int i = lane; i < 256; i += 64){
    int e = (xu[i] >> 7) & 0xFF;
    cnt += (e >= 0x60 && e <= 0x8F) ? 1 : 0;
  }
  #pragma unroll
  for (int off = 32; off; off >>= 1) cnt += __shfl_xor(cnt, off, 64);
  unsigned odd = eu[2 * lane + 1];
  #pragma unroll
  for (int off = 32; off; off >>= 1) odd |= __shfl_xor(odd, off, 64);
  if (lane == 0){
    flags[0] = (cnt < 218) ? 1 : 0;   // 1 = floats are f32
    flags[1] = (odd == 0)  ? 1 : 0;   // 1 = edges are int64
  }
}

__device__ __forceinline__ bf16 cvt_b(const void* src, int i, int f32m){
  if (f32m) return __float2bfloat16(((const float*)src)[i]);
  return ((const bf16*)src)[i];
}

// convert (weights only) + histogram over dst read straight from d_in
__global__ __launch_bounds__(256) void k_convert(
    const void* __restrict__ W1,
    const void* __restrict__ as1,const void* __restrict__ ad1,
    const void* __restrict__ b1, const void* __restrict__ W2,
    const void* __restrict__ as2,const void* __restrict__ ad2,
    const void* __restrict__ b2, const void* __restrict__ ei,
    char* __restrict__ ws){
  const int* flags = (const int*)(ws + WS_FLAGS);
  int f32m = flags[0], i64m = flags[1];
  bf16* w1t  = (bf16*)(ws + WS_W1T);
  bf16* as1n = (bf16*)(ws + WS_AS1N);
  bf16* ad1n = (bf16*)(ws + WS_AD1N);
  bf16* b1n  = (bf16*)(ws + WS_B1N);
  bf16* w2t  = (bf16*)(ws + WS_W2T);
  bf16* as2n = (bf16*)(ws + WS_AS2N);
  bf16* ad2n = (bf16*)(ws + WS_AD2N);
  bf16* b2n  = (bf16*)(ws + WS_B2N);
  int*  counts=(int*) (ws + WS_COUNTS);
  for (int g = blockIdx.x * 256 + threadIdx.x; g < CV_END; g += gridDim.x * 256){
    if      (g < CV_AS1){ int i = g-CV_W1; int k = i >> 8, n = i & 255;
      w1t[n*CIN + k] = cvt_b(W1, i, f32m); }                       // transpose
    else if (g < CV_AD1) as1n[g-CV_AS1] = cvt_b(as1,g-CV_AS1, f32m);
    else if (g < CV_B1 ) ad1n[g-CV_AD1] = cvt_b(ad1,g-CV_AD1, f32m);
    else if (g < CV_W2 ) b1n [g-CV_B1 ] = cvt_b(b1, g-CV_B1,  f32m);
    else if (g < CV_AS2){ int i = g-CV_W2; int k = i / NOUT, n = i - k*NOUT;
      w2t[n*CIN + k] = cvt_b(W2, i, f32m); }                       // transpose (rows 40..47 pre-zeroed)
    else if (g < CV_AD2) as2n[g-CV_AS2] = cvt_b(as2,g-CV_AS2, f32m);
    else if (g < CV_B2 ) ad2n[g-CV_AD2] = cvt_b(ad2,g-CV_AD2, f32m);
    else if (g < CV_HIST) b2n[g-CV_B2 ] = cvt_b(b2, g-CV_B2,  f32m);
    else { int i = g-CV_HIST;
      int d = i64m ? (int)((const long long*)ei)[(size_t)NE+i] : ((const int*)ei)[NE+i];
      atomicAdd(&counts[d], 1); }
  }
}

// ---------------- parallel CSR scan (real edges only; self-loops analytic) -----
__global__ __launch_bounds__(256) void k_scan_part(const int* __restrict__ counts, int* __restrict__ bsum){
  __shared__ int lds[256];
  int t = threadIdx.x;
  int idx = blockIdx.x * 256 + t;
  int v = (idx < NN) ? counts[idx] : 0;
  lds[t] = v;
  #pragma unroll
  for (int s = 128; s > 0; s >>= 1){
    __syncthreads();
    if (t < s) lds[t] += lds[t + s];
  }
  if (t == 0) bsum[blockIdx.x] = lds[0];
}

__global__ __launch_bounds__(256) void k_scan_mid(const int* __restrict__ bsum, int* __restrict__ boff,
                                                  int* __restrict__ row_ptr){
  __shared__ int lds[256];
  int t = threadIdx.x;
  int v = (t < SCB) ? bsum[t] : 0;
  lds[t] = v;
  for (int off = 1; off < 256; off <<= 1){
    __syncthreads();
    int u = (t >= off) ? lds[t - off] : 0;
    __syncthreads();
    lds[t] += u;
  }
  __syncthreads();
  if (t < SCB) boff[t] = lds[t] - v;   // exclusive
  if (t == 0) row_ptr[NN] = NE;
}

__global__ __launch_bounds__(256) void k_scan_apply(const int* __restrict__ counts, const int* __restrict__ boff,
                                                    int* __restrict__ row_ptr){
  __shared__ int lds[256];
  int t = threadIdx.x;
  int idx = blockIdx.x * 256 + t;
  int v = (idx < NN) ? counts[idx] : 0;
  lds[t] = v;
  for (int off = 1; off < 256; off <<= 1){
    __syncthreads();
    int u = (t >= off) ? lds[t - off] : 0;
    __syncthreads();
    lds[t] += u;
  }
  __syncthreads();
  if (idx < NN) row_ptr[idx] = boff[blockIdx.x] + lds[t] - v;
}

// ---------------- bucket partition (block-local lines -> merged writebacks) ----
__global__ __launch_bounds__(256) void k_lhist(const void* __restrict__ ei, const int* __restrict__ flags,
                                               int* __restrict__ gcnt){
  __shared__ int h[256];
  int tid = threadIdx.x, blk = blockIdx.x;
  h[tid] = 0;
  __syncthreads();
  int i0 = blk * CH, i1 = min(i0 + CH, NE);
  int i64m = flags[1];
  for (int i = i0 + tid; i < i1; i += 256){
    int d = i64m ? (int)((const long long*)ei)[(size_t)NE + i] : ((const int*)ei)[NE + i];
    atomicAdd(&h[d >> 8], 1);
  }
  __syncthreads();
  gcnt[tid * B1 + blk] = h[tid];    // layout [bucket][block]
}

__global__ __launch_bounds__(256) void k_gscan(const int* __restrict__ gcnt, int* __restrict__ roff,
                                               int* __restrict__ bbase){
  __shared__ int lds[256];
  int t = threadIdx.x;
  int tot = 0;
  for (int blk = 0; blk < B1; ++blk) tot += gcnt[t * B1 + blk];
  lds[t] = tot;
  for (int off = 1; off < 256; off <<= 1){
    __syncthreads();
    int u = (t >= off) ? lds[t - off] : 0;
    __syncthreads();
    lds[t] += u;
  }
  __syncthreads();
  int base = lds[t] - tot;          // exclusive over buckets
  bbase[t] = base;
  if (t == 255) bbase[256] = NE;
  int run = base;
  for (int blk = 0; blk < B1; ++blk){
    roff[t * B1 + blk] = run;
    run += gcnt[t * B1 + blk];
  }
}

__global__ __launch_bounds__(256) void k_bscatter(const void* __restrict__ ei, const int* __restrict__ flags,
                                                  const int* __restrict__ roff, int2* __restrict__ ebuf){
  __shared__ int lcur[256];
  int tid = threadIdx.x, blk = blockIdx.x;
  lcur[tid] = roff[tid * B1 + blk];
  __syncthreads();
  int i0 = blk * CH, i1 = min(i0 + CH, NE);
  int i64m = flags[1];
  for (int i = i0 + tid; i < i1; i += 256){
    int s, d;
    if (i64m){ s = (int)((const long long*)ei)[i]; d = (int)((const long long*)ei)[(size_t)NE + i]; }
    else     { s = ((const int*)ei)[i];            d = ((const int*)ei)[NE + i]; }
    int pos = atomicAdd(&lcur[d >> 8], 1);
    ebuf[pos] = make_int2(s, d);
  }
}

__global__ __launch_bounds__(256) void k_refine(const int2* __restrict__ ebuf, const int* __restrict__ bbase,
                                                const int* __restrict__ row_ptr, int* __restrict__ cursor,
                                                int* __restrict__ eidx){
  int b = blockIdx.x;
  int p0 = bbase[b], p1 = bbase[b + 1];
  for (int p = p0 + threadIdx.x; p < p1; p += 256){
    int2 e = ebuf[p];
    int pos = row_ptr[e.y] + atomicAdd(&cursor[e.y], 1);
    eidx[pos] = e.x;
  }
}

// ---------------- GEMM1 (MFMA, LDS-staged) + fused al1 + fp8 h1 store ---------
constexpr int G1R = 64;                 // rows per block
constexpr int LP  = 72;                 // padded LDS row (elems)
__global__ __launch_bounds__(256) void k_gemm1(const void* __restrict__ xin,
                                               const int* __restrict__ flags,
                                               const bf16* __restrict__ w1t,
                                               const bf16* __restrict__ as1, const bf16* __restrict__ ad1,
                                               unsigned char* __restrict__ h1q,
                                               float* __restrict__ al_s1, float* __restrict__ al_d1){
  __shared__ short Ab[G1R * LP];
  __shared__ short Bb[256 * LP];
  int tid  = threadIdx.x;
  int w    = tid >> 6, lane = tid & 63, quad = lane >> 4, c = lane & 15;
  int row0 = blockIdx.x * G1R;
  int f32m = flags[0];

  v4f acc[4][4];
  #pragma unroll
  for (int mt = 0; mt < 4; ++mt)
    #pragma unroll
    for (int nt = 0; nt < 4; ++nt) acc[mt][nt] = (v4f){0.f,0.f,0.f,0.f};

  int arow = tid >> 2;
  int aseg = tid & 3;
  int grow = row0 + arow; if (grow >= NN) grow = NN - 1;

  for (int ph = 0; ph < 4; ++ph){
    if (ph) __syncthreads();
    {
      short va[16];
      if (f32m){
        const float* src = (const float*)xin + (size_t)grow * CIN + ph*64 + aseg*16;
        #pragma unroll
        for (int i = 0; i < 4; ++i){
          float4 f = *reinterpret_cast<const float4*>(src + i*4);
          va[i*4+0] = (short)f2bits(f.x); va[i*4+1] = (short)f2bits(f.y);
          va[i*4+2] = (short)f2bits(f.z); va[i*4+3] = (short)f2bits(f.w);
        }
      } else {
        const short* src = (const short*)xin + (size_t)grow * CIN + ph*64 + aseg*16;
        v8s u0 = *reinterpret_cast<const v8s*>(src);
        v8s u1 = *reinterpret_cast<const v8s*>(src + 8);
        #pragma unroll
        for (int i = 0; i < 8; ++i){ va[i] = u0[i]; va[8+i] = u1[i]; }
      }
      short* dst = &Ab[arow * LP + aseg * 16];
      *reinterpret_cast<v8s*>(dst)     = *reinterpret_cast<v8s*>(&va[0]);
      *reinterpret_cast<v8s*>(dst + 8) = *reinterpret_cast<v8s*>(&va[8]);
    }
    {
      const short* src = (const short*)w1t + (size_t)tid * CIN + ph*64;
      short* dst = &Bb[tid * LP];
      #pragma unroll
      for (int j = 0; j < 8; ++j)
        *reinterpret_cast<v8s*>(dst + j*8) = *reinterpret_cast<const v8s*>(src + j*8);
    }
    __syncthreads();
    #pragma unroll
    for (int s = 0; s < 2; ++s){
      int ch = s*4 + quad;
      v8s af[4], bfb[4];
      #pragma unroll
      for (int mt = 0; mt < 4; ++mt)
        af[mt] = *reinterpret_cast<const v8s*>(&Ab[(mt*16 + c) * LP + ch*8]);
      #pragma unroll
      for (int nt = 0; nt < 4; ++nt)
        bfb[nt] = *reinterpret_cast<const v8s*>(&Bb[(w*64 + nt*16 + c) * LP + ch*8]);
      #pragma unroll
      for (int mt = 0; mt < 4; ++mt)
        #pragma unroll
        for (int nt = 0; nt < 4; ++nt)
          acc[mt][nt] = __builtin_amdgcn_mfma_f32_16x16x32_bf16(af[mt], bfb[nt], acc[mt][nt], 0, 0, 0);
    }
  }

  float as1v[4], ad1v[4];
  #pragma unroll
  for (int nt = 0; nt < 4; ++nt){
    as1v[nt] = b2f(as1[w*64 + nt*16 + c]);
    ad1v[nt] = b2f(ad1[w*64 + nt*16 + c]);
  }
  #pragma unroll
  for (int mt = 0; mt < 4; ++mt){
    #pragma unroll
    for (int r = 0; r < 4; ++r){
      float ps = 0.f, pd = 0.f;
      #pragma unroll
      for (int nt = 0; nt < 4; ++nt){ ps += acc[mt][nt][r] * as1v[nt]; pd += acc[mt][nt][r] * ad1v[nt]; }
      #pragma unroll
      for (int off = 1; off < 16; off <<= 1){ ps += __shfl_xor(ps, off, 64); pd += __shfl_xor(pd, off, 64); }
      int row = row0 + mt*16 + quad*4 + r;
      if (c == 0 && row < NN){
        al_s1[row * NH + w] = ps;
        al_d1[row * NH + w] = pd;
      }
    }
  }
  #pragma unroll
  for (int mt = 0; mt < 4; ++mt){
    #pragma unroll
    for (int nt = 0; nt < 4; ++nt){
      #pragma unroll
      for (int r = 0; r < 4; r += 2){
        int row = row0 + mt*16 + quad*4 + r;
        if (row + 1 < NN){
          int pk = __builtin_amdgcn_cvt_pk_fp8_f32(acc[mt][nt][r], acc[mt][nt][r+1], 0, false);
          size_t col = w*64 + nt*16 + c;
          h1q[(size_t)row       * HC + col] = (unsigned char)(pk & 0xFF);
          h1q[(size_t)(row + 1) * HC + col] = (unsigned char)((pk >> 8) & 0xFF);
        } else if (row < NN){
          int pk = __builtin_amdgcn_cvt_pk_fp8_f32(acc[mt][nt][r], acc[mt][nt][r], 0, false);
          h1q[(size_t)row * HC + w*64 + nt*16 + c] = (unsigned char)(pk & 0xFF);
        }
      }
    }
  }
}

// ---------------- edge weights layer 1 (node-parallel: coalesced ew writes) ----
__global__ __launch_bounds__(256) void k_ew1(const int* __restrict__ row_ptr, const int* __restrict__ eidx,
                                             const float* __restrict__ al_s1, const float* __restrict__ al_d1,
                                             float4* __restrict__ ew1){
  int lane = threadIdx.x & 63;
  int n = blockIdx.x * 4 + (threadIdx.x >> 6);
  int p0 = __builtin_amdgcn_readfirstlane(row_ptr[n]);
  int p1 = __builtin_amdgcn_readfirstlane(row_ptr[n + 1]);
  float4 ad = reinterpret_cast<const float4*>(al_d1)[n];   // wave-uniform
  for (int p = p0 + lane; p < p1; p += 64){
    int s = eidx[p];
    float4 as = reinterpret_cast<const float4*>(al_s1)[s];
    float4 w;
    w.x = __expf(lrelu(as.x + ad.x));
    w.y = __expf(lrelu(as.y + ad.y));
    w.z = __expf(lrelu(as.z + ad.z));
    w.w = __expf(lrelu(as.w + ad.w));
    ew1[p] = w;
  }
}

// ---------------- gather layer 1 (+ analytic self-loop), 4-deep MLP ------------
__global__ __launch_bounds__(256) void k_gather1(const int* __restrict__ row_ptr, const int* __restrict__ eidx,
                                                 const float* __restrict__ ew1,
                                                 const float* __restrict__ al_s1, const float* __restrict__ al_d1,
                                                 const unsigned* __restrict__ h1v, const bf16* __restrict__ b1,
                                                 bf16* __restrict__ y1){
  int lane = threadIdx.x & 63;
  int n = blockIdx.x * 4 + (threadIdx.x >> 6);
  int h = lane >> 4;
  int p0 = __builtin_amdgcn_readfirstlane(row_ptr[n]);
  int p1 = __builtin_amdgcn_readfirstlane(row_ptr[n + 1]);
  // self-loop contribution (src == dst == n)
  float wss = __expf(lrelu(al_s1[n * NH + h] + al_d1[n * NH + h]));
  unsigned us = h1v[(size_t)n * 64 + lane];
  float den = wss;
  float a0 = wss * __builtin_amdgcn_cvt_f32_fp8(us, 0);
  float a1 = wss * __builtin_amdgcn_cvt_f32_fp8(us, 1);
  float a2 = wss * __builtin_amdgcn_cvt_f32_fp8(us, 2);
  float a3 = wss * __builtin_amdgcn_cvt_f32_fp8(us, 3);
  int p = p0;
  for (; p + 3 < p1; p += 4){
    int sA = __builtin_amdgcn_readfirstlane(eidx[p]);
    int sB = __builtin_amdgcn_readfirstlane(eidx[p + 1]);
    int sC = __builtin_amdgcn_readfirstlane(eidx[p + 2]);
    int sD = __builtin_amdgcn_readfirstlane(eidx[p + 3]);
    float wA = ew1[(size_t)p * 4 + h];
    float wB = ew1[(size_t)(p + 1) * 4 + h];
    float wC = ew1[(size_t)(p + 2) * 4 + h];
    float wD = ew1[(size_t)(p + 3) * 4 + h];
    unsigned uA = h1v[(size_t)sA * 64 + lane];
    unsigned uB = h1v[(size_t)sB * 64 + lane];
    unsigned uC = h1v[(size_t)sC * 64 + lane];
    unsigned uD = h1v[(size_t)sD * 64 + lane];
    den += (wA + wB) + (wC + wD);
    a0 += wA * __builtin_amdgcn_cvt_f32_fp8(uA, 0) + wB * __builtin_amdgcn_cvt_f32_fp8(uB, 0)
        + wC * __builtin_amdgcn_cvt_f32_fp8(uC, 0) + wD * __builtin_amdgcn_cvt_f32_fp8(uD, 0);
    a1 += wA * __builtin_amdgcn_cvt_f32_fp8(uA, 1) + wB * __builtin_amdgcn_cvt_f32_fp8(uB, 1)
        + wC * __builtin_amdgcn_cvt_f32_fp8(uC, 1) + wD * __builtin_amdgcn_cvt_f32_fp8(uD, 1);
    a2 += wA * __builtin_amdgcn_cvt_f32_fp8(uA, 2) + wB * __builtin_amdgcn_cvt_f32_fp8(uB, 2)
        + wC * __builtin_amdgcn_cvt_f32_fp8(uC, 2) + wD * __builtin_amdgcn_cvt_f32_fp8(uD, 2);
    a3 += wA * __builtin_amdgcn_cvt_f32_fp8(uA, 3) + wB * __builtin_amdgcn_cvt_f32_fp8(uB, 3)
        + wC * __builtin_amdgcn_cvt_f32_fp8(uC, 3) + wD * __builtin_amdgcn_cvt_f32_fp8(uD, 3);
  }
  for (; p < p1; ++p){
    int s = __builtin_amdgcn_readfirstlane(eidx[p]);
    float w = ew1[(size_t)p * 4 + h];
    unsigned u = h1v[(size_t)s * 64 + lane];
    den += w;
    a0 += w * __builtin_amdgcn_cvt_f32_fp8(u, 0);
    a1 += w * __builtin_amdgcn_cvt_f32_fp8(u, 1);
    a2 += w * __builtin_amdgcn_cvt_f32_fp8(u, 2);
    a3 += w * __builtin_amdgcn_cvt_f32_fp8(u, 3);
  }
  float inv = 1.f / (den + 1e-16f);
  ushort4 bb = reinterpret_cast<const ushort4*>(b1)[lane];
  ushort4 o;
  o.x = f2bits(fmaxf(a0 * inv + bits2f(bb.x), 0.f));
  o.y = f2bits(fmaxf(a1 * inv + bits2f(bb.y), 0.f));
  o.z = f2bits(fmaxf(a2 * inv + bits2f(bb.z), 0.f));
  o.w = f2bits(fmaxf(a3 * inv + bits2f(bb.w), 0.f));
  reinterpret_cast<ushort4*>(y1)[(size_t)n * 64 + lane] = o;
}

// ---------------- GEMM2 (MFMA, W2T in LDS) + fused al2 + fp8 h2 (64B rows) -----
constexpr int W2LP = 260;
__global__ __launch_bounds__(256) void k_gemm2(const bf16* __restrict__ y1, const bf16* __restrict__ w2t,
                                               const bf16* __restrict__ as2, const bf16* __restrict__ ad2,
                                               unsigned char* __restrict__ h2q, float* __restrict__ al_s2,
                                               float* __restrict__ al_d2){
  __shared__ short Wb[NPAD * W2LP];
  int tid = threadIdx.x;
  int w = tid >> 6, lane = tid & 63, quad = lane >> 4, c = lane & 15;
  int m0 = blockIdx.x * 64 + w * 16;
  for (int idx = tid; idx < NPAD * 32; idx += 256){
    int n = idx >> 5, sg = idx & 31;
    *reinterpret_cast<v8s*>(&Wb[n * W2LP + sg * 8]) =
      *reinterpret_cast<const v8s*>((const short*)w2t + (size_t)n * CIN + sg * 8);
  }
  int arow = m0 + c; if (arow >= NN) arow = NN - 1;
  const short* ar = (const short*)y1 + (size_t)arow * HC + quad * 8;
  v8s a[8];
  #pragma unroll
  for (int i = 0; i < 8; ++i) a[i] = *reinterpret_cast<const v8s*>(ar + i * 32);
  __syncthreads();

  v4f acc[3];
  #pragma unroll
  for (int t = 0; t < 3; ++t) acc[t] = (v4f){0.f, 0.f, 0.f, 0.f};
  #pragma unroll
  for (int k = 0; k < 8; ++k){
    int ch = k*4 + quad;
    #pragma unroll
    for (int t = 0; t < 3; ++t){
      v8s b = *reinterpret_cast<const v8s*>(&Wb[(t*16 + c) * W2LP + ch * 8]);
      acc[t] = __builtin_amdgcn_mfma_f32_16x16x32_bf16(a[k], b, acc[t], 0, 0, 0);
    }
  }
  float as2f[3], ad2f[3];
  #pragma unroll
  for (int t = 0; t < 3; ++t){
    int col = t*16 + c;
    as2f[t] = (col < NOUT) ? b2f(as2[col]) : 0.f;
    ad2f[t] = (col < NOUT) ? b2f(ad2[col]) : 0.f;
  }
  #pragma unroll
  for (int r = 0; r < 4; ++r){
    int row = m0 + quad*4 + r;
    float ps = 0.f, pd = 0.f;
    #pragma unroll
    for (int t = 0; t < 3; ++t){ ps += acc[t][r] * as2f[t]; pd += acc[t][r] * ad2f[t]; }
    #pragma unroll
    for (int off = 1; off < 16; off <<= 1){ ps += __shfl_xor(ps, off, 64); pd += __shfl_xor(pd, off, 64); }
    if (row < NN && c == 0){ al_s2[row] = ps; al_d2[row] = pd; }
  }
  // fp8 h2 store (64B rows; alphas above computed from fp32 accs)
  #pragma unroll
  for (int t = 0; t < 3; ++t){
    int col = t*16 + c;
    if (col < NOUT){
      #pragma unroll
      for (int r = 0; r < 4; r += 2){
        int row = m0 + quad*4 + r;
        int pk = __builtin_amdgcn_cvt_pk_fp8_f32(acc[t][r], acc[t][r+1], 0, false);
        if (row < NN)     h2q[(size_t)row       * 64 + col] = (unsigned char)(pk & 0xFF);
        if (row + 1 < NN) h2q[(size_t)(row + 1) * 64 + col] = (unsigned char)((pk >> 8) & 0xFF);
      }
    }
  }
}

// ---------------- edge weights layer 2 (node-parallel) ----------------
__global__ __launch_bounds__(256) void k_ew2(const int* __restrict__ row_ptr, const int* __restrict__ eidx,
                                             const float* __restrict__ al_s2, const float* __restrict__ al_d2,
                                             float* __restrict__ ew2){
  int lane = threadIdx.x & 63;
  int n = blockIdx.x * 4 + (threadIdx.x >> 6);
  int p0 = __builtin_amdgcn_readfirstlane(row_ptr[n]);
  int p1 = __builtin_amdgcn_readfirstlane(row_ptr[n + 1]);
  float ad = al_d2[n];   // wave-uniform
  for (int p = p0 + lane; p < p1; p += 64)
    ew2[p] = __expf(lrelu(al_s2[eidx[p]] + ad));
}

// ---------------- gather layer 2: quad-parallel (4 edges in flight x2 unroll) ---
// Lane (q = lane>>4, c = lane&15): quad q handles edges p0+q, p0+q+4, ...
// Lane c<10 loads one dword = 4 fp8 cols [4c..4c+3] of the 64B h2 row (1 line).
// Cross-quad reduce via shfl_xor(16,32), then log_softmax and 4-col store.
__global__ __launch_bounds__(256) void k_gather2(const int* __restrict__ row_ptr, const int* __restrict__ eidx,
                                                 const float* __restrict__ ew2,
                                                 const float* __restrict__ al_s2, const float* __restrict__ al_d2,
                                                 const unsigned char* __restrict__ h2q, const bf16* __restrict__ b2v,
                                                 const int* __restrict__ flags, void* __restrict__ out){
  int lane = threadIdx.x & 63;
  int n = blockIdx.x * 4 + (threadIdx.x >> 6);
  int q = lane >> 4, c = lane & 15;
  bool act = (c < 10);                      // 10 dwords cover the 40 cols
  int p0 = __builtin_amdgcn_readfirstlane(row_ptr[n]);
  int p1 = __builtin_amdgcn_readfirstlane(row_ptr[n + 1]);
  const unsigned* h2v = reinterpret_cast<const unsigned*>(h2q);
  float den = 0.f, a0 = 0.f, a1 = 0.f, a2 = 0.f, a3 = 0.f;
  if (q == 0){                              // analytic self-loop, counted once
    float wss = __expf(lrelu(al_s2[n] + al_d2[n]));
    den = wss;
    if (act){
      unsigned u = h2v[(size_t)n * 16 + c];
      a0 = wss * __builtin_amdgcn_cvt_f32_fp8(u, 0);
      a1 = wss * __builtin_amdgcn_cvt_f32_fp8(u, 1);
      a2 = wss * __builtin_amdgcn_cvt_f32_fp8(u, 2);
      a3 = wss * __builtin_amdgcn_cvt_f32_fp8(u, 3);
    }
  }
  int p = p0 + q;
  for (; p + 4 < p1; p += 8){
    int sA = eidx[p], sB = eidx[p + 4];
    float wA = ew2[p], wB = ew2[p + 4];
    unsigned uA = act ? h2v[(size_t)sA * 16 + c] : 0u;
    unsigned uB = act ? h2v[(size_t)sB * 16 + c] : 0u;
    den += wA + wB;
    a0 += wA * __builtin_amdgcn_cvt_f32_fp8(uA, 0) + wB * __builtin_amdgcn_cvt_f32_fp8(uB, 0);
    a1 += wA * __builtin_amdgcn_cvt_f32_fp8(uA, 1) + wB * __builtin_amdgcn_cvt_f32_fp8(uB, 1);
    a2 += wA * __builtin_amdgcn_cvt_f32_fp8(uA, 2) + wB * __builtin_amdgcn_cvt_f32_fp8(uB, 2);
    a3 += wA * __builtin_amdgcn_cvt_f32_fp8(uA, 3) + wB * __builtin_amdgcn_cvt_f32_fp8(uB, 3);
  }
  if (p < p1){
    int s = eidx[p];
    float w = ew2[p];
    unsigned u = act ? h2v[(size_t)s * 16 + c] : 0u;
    den += w;
    a0 += w * __builtin_amdgcn_cvt_f32_fp8(u, 0);
    a1 += w * __builtin_amdgcn_cvt_f32_fp8(u, 1);
    a2 += w * __builtin_amdgcn_cvt_f32_fp8(u, 2);
    a3 += w * __builtin_amdgcn_cvt_f32_fp8(u, 3);
  }
  // reduce across the 4 quads (lanes within a quad hold identical den)
  #pragma unroll
  for (int off = 16; off <= 32; off <<= 1){
    den += __shfl_xor(den, off, 64);
    a0  += __shfl_xor(a0,  off, 64);
    a1  += __shfl_xor(a1,  off, 64);
    a2  += __shfl_xor(a2,  off, 64);
    a3  += __shfl_xor(a3,  off, 64);
  }
  float inv = 1.f / (den + 1e-16f);
  float v0 = -INFINITY, v1 = -INFINITY, v2 = -INFINITY, v3 = -INFINITY;
  if (act){
    ushort4 bb = *reinterpret_cast<const ushort4*>(reinterpret_cast<const unsigned short*>(b2v) + 4 * c);
    v0 = a0 * inv + bits2f(bb.x);
    v1 = a1 * inv + bits2f(bb.y);
    v2 = a2 * inv + bits2f(bb.z);
    v3 = a3 * inv + bits2f(bb.w);
  }
  float M = wave_max(fmaxf(fmaxf(v0, v1), fmaxf(v2, v3)));
  float ex = (q == 0 && act)
           ? (__expf(v0 - M) + __expf(v1 - M)) + (__expf(v2 - M) + __expf(v3 - M)) : 0.f;
  float S = wave_sum(ex);
  if (q == 0 && act){
    float lg = M + __logf(S);
    if (flags[0]){
      float4 o = {v0 - lg, v1 - lg, v2 - lg, v3 - lg};
      *reinterpret_cast<float4*>((float*)out + (size_t)n * NOUT + 4 * c) = o;
    } else {
      ushort4 o;
      o.x = f2bits(v0 - lg); o.y = f2bits(v1 - lg);
      o.z = f2bits(v2 - lg); o.w = f2bits(v3 - lg);
      *reinterpret_cast<ushort4*>((unsigned short*)out + (size_t)n * NOUT + 4 * c) = o;
    }
  }
}

extern "C" void kernel_launch(void* const* d_in, const int* in_sizes, int n_in,
                              void* d_out, int out_size, void* d_ws, size_t ws_size,
                              hipStream_t stream) {
  const void* x   = d_in[0];
  const void* ei  = d_in[1];
  const void* W1  = d_in[2];
  const void* as1 = d_in[3];
  const void* ad1 = d_in[4];
  const void* b1  = d_in[5];
  const void* W2  = d_in[6];
  const void* as2 = d_in[7];
  const void* ad2 = d_in[8];
  const void* b2  = d_in[9];

  char* ws = (char*)d_ws;
  int*   flags   = (int*)  (ws + WS_FLAGS);
  float* ew1     = (float*)(ws + WS_EW1);
  bf16*  w1t     = (bf16*) (ws + WS_W1T);
  bf16*  as1n    = (bf16*) (ws + WS_AS1N);
  bf16*  ad1n    = (bf16*) (ws + WS_AD1N);
  bf16*  b1n     = (bf16*) (ws + WS_B1N);
  bf16*  w2t     = (bf16*) (ws + WS_W2T);
  bf16*  as2n    = (bf16*) (ws + WS_AS2N);
  bf16*  ad2n    = (bf16*) (ws + WS_AD2N);
  bf16*  b2n     = (bf16*) (ws + WS_B2N);
  int*   counts  = (int*)  (ws + WS_COUNTS);
  int*   cursor  = (int*)  (ws + WS_CURSOR);
  int*   row_ptr = (int*)  (ws + WS_ROWPTR);
  int*   eidx    = (int*)  (ws + WS_EIDX);
  unsigned char* h1q = (unsigned char*)(ws + WS_H1);
  float* al_s1   = (float*)(ws + WS_ALS1);
  float* al_d1   = (float*)(ws + WS_ALD1);
  bf16*  y1      = (bf16*) (ws + WS_Y1);
  unsigned char* h2q = (unsigned char*)(ws + WS_H2);
  float* al_s2   = (float*)(ws + WS_ALS2);
  float* al_d2   = (float*)(ws + WS_ALD2);
  float* ew2     = (float*)(ws + WS_EW2);
  int*   bsum    = (int*)  (ws + WS_BSUM);
  int*   boff    = (int*)  (ws + WS_BOFF);
  int*   gcnt    = (int*)  (ws + WS_GCNT);
  int*   roff    = (int*)  (ws + WS_ROFF);
  int*   bbase   = (int*)  (ws + WS_BBASE);
  int2*  ebuf    = (int2*) (ws + WS_EBUF);

  hipMemsetAsync(counts, 0, (size_t)NN * 4, stream);
  hipMemsetAsync(cursor, 0, (size_t)NN * 4, stream);
  hipMemsetAsync(w2t,    0, (size_t)NPAD * CIN * 2, stream);

  k_detect <<<1, 64, 0, stream>>>((const unsigned short*)x, (const unsigned*)ei, flags);
  k_convert<<<1024, 256, 0, stream>>>(W1, as1, ad1, b1, W2, as2, ad2, b2, ei, ws);

  k_lhist   <<<B1, 256, 0, stream>>>(ei, flags, gcnt);
  k_gscan   <<<1, 256, 0, stream>>>(gcnt, roff, bbase);
  k_scan_part <<<SCB, 256, 0, stream>>>(counts, bsum);
  k_scan_mid  <<<1, 256, 0, stream>>>(bsum, boff, row_ptr);
  k_scan_apply<<<SCB, 256, 0, stream>>>(counts, boff, row_ptr);
  k_bscatter<<<B1, 256, 0, stream>>>(ei, flags, roff, ebuf);
  k_refine  <<<NB, 256, 0, stream>>>(ebuf, bbase, row_ptr, cursor, eidx);

  k_gemm1  <<<(NN + G1R - 1) / G1R, 256, 0, stream>>>(x, flags, w1t, as1n, ad1n, h1q, al_s1, al_d1);
  k_ew1    <<<NN / 4, 256, 0, stream>>>(row_ptr, eidx, al_s1, al_d1, (float4*)ew1);
  k_gather1<<<NN / 4, 256, 0, stream>>>(row_ptr, eidx, ew1, al_s1, al_d1, (const unsigned*)h1q, b1n, y1);
  k_gemm2  <<<(NN + 63) / 64, 256, 0, stream>>>(y1, w2t, as2n, ad2n, h2q, al_s2, al_d2);
  k_ew2    <<<NN / 4, 256, 0, stream>>>(row_ptr, eidx, al_s2, al_d2, ew2);
  k_gather2<<<NN / 4, 256, 0, stream>>>(row_ptr, eidx, ew2, al_s2, al_d2, h2q, b2n, flags, d_out);
}